// Round 11
// baseline (222.357 us; speedup 1.0000x reference)
//
#include <hip/hip_runtime.h>

typedef __attribute__((ext_vector_type(8))) __bf16 bf16x8;
typedef __attribute__((ext_vector_type(4))) __bf16 bf16x4;
typedef __attribute__((ext_vector_type(4))) float f32x4;

__device__ __forceinline__ bf16x8 cvt8(const float* __restrict__ p)
{
    const float4 a = *(const float4*)p;
    const float4 b = *(const float4*)(p + 4);
    bf16x8 r;
    r[0] = (__bf16)a.x; r[1] = (__bf16)a.y; r[2] = (__bf16)a.z; r[3] = (__bf16)a.w;
    r[4] = (__bf16)b.x; r[5] = (__bf16)b.y; r[6] = (__bf16)b.z; r[7] = (__bf16)b.w;
    return r;
}

// async 16B global->LDS (global_load_lds_dwordx4); LDS dest wave-uniform base
// + lane*16 (lane-contiguous chunks, unpadded LDS). Global source IS per-lane.
__device__ __forceinline__ void gld16(const __bf16* g, __bf16* l)
{
    __builtin_amdgcn_global_load_lds(
        (const __attribute__((address_space(1))) void*)g,
        (__attribute__((address_space(3))) void*)l, 16, 0, 0);
}

// ---------------------------------------------------------------------------
// Stage 0: fp32 -> bf16 conversion of X and Wqkv only (Wout conversion is
// folded into the gemm_qkv launch). grid (1024, 4) x 256.
// ---------------------------------------------------------------------------
struct CvtArgs {
    const float* s[4];
    __bf16* d[4];
    int n[4];
};

__global__ __launch_bounds__(256) void cvt_bf16(CvtArgs a)
{
    const int t = blockIdx.y;
    const int i0 = (blockIdx.x * 256 + threadIdx.x) * 8;
    if (i0 < a.n[t])
        *(bf16x8*)(a.d[t] + i0) = cvt8(a.s[t] + i0);
}

// ---------------------------------------------------------------------------
// 128x64 bf16 GEMM core: same proven structure (double-buffered gld16, BK=32,
// ONE barrier per K-step, 4 waves) but half the N-tile -> 2x the grid, fixing
// the 1.5-2 block/CU occupancy cliff (m102) with ZERO extra global traffic
// (unlike r7's split-K).  Waves 2(M)x2(N): wave = 64x32 via acc[4][2].
// LDS 24.6KB.  C = A @ B^T, C type CT.  Per-element math bitwise identical
// to the 128x128 core (same fragment decomposition, same K-order).
// ---------------------------------------------------------------------------
template <typename CT>
__device__ __forceinline__ void gemm_core(const __bf16* __restrict__ Ap, int lda,
                                          const __bf16* __restrict__ Bp, int ldb,
                                          CT* __restrict__ Cp, int ldc, int K)
{
    __shared__ __bf16 As[2][128 * 32];
    __shared__ __bf16 Bs[2][64 * 32];
    const int tid  = threadIdx.x;
    const int w    = tid >> 6;
    const int lane = tid & 63;
    const int ln   = lane & 15;
    const int quad = lane >> 4;
    const int wm   = w & 1;
    const int wn   = w >> 1;   // 0..1 (w>=2 -> wn in {1}, w in {2,3} -> wn 1; w0,1 -> 0)

    f32x4 acc[4][2];
    const f32x4 zero = {0.f, 0.f, 0.f, 0.f};
#pragma unroll
    for (int i = 0; i < 4; i++)
#pragma unroll
        for (int j = 0; j < 2; j++) acc[i][j] = zero;

    // A: 128x32 = 512 x 16B chunks (2/thread); B: 64x32 = 256 chunks (1/thread)
    auto stage = [&](int buf, int k0) {
#pragma unroll
        for (int i = 0; i < 2; i++) {
            const int l = tid + i * 256;
            gld16(Ap + (size_t)(l >> 2) * lda + k0 + (l & 3) * 8, As[buf] + l * 8);
        }
        gld16(Bp + (size_t)(tid >> 2) * ldb + k0 + (tid & 3) * 8, Bs[buf] + tid * 8);
    };

    stage(0, 0);
    int buf = 0;
    for (int k0 = 0; k0 < K; k0 += 32, buf ^= 1) {
        __syncthreads();
        if (k0 + 32 < K) stage(buf ^ 1, k0 + 32);

        bf16x8 af[4], bw[2];
#pragma unroll
        for (int i = 0; i < 4; i++)
            af[i] = *(const bf16x8*)(As[buf] + (wm * 64 + i * 16 + ln) * 32 + quad * 8);
#pragma unroll
        for (int j = 0; j < 2; j++)
            bw[j] = *(const bf16x8*)(Bs[buf] + (wn * 32 + j * 16 + ln) * 32 + quad * 8);
#pragma unroll
        for (int i = 0; i < 4; i++)
#pragma unroll
            for (int j = 0; j < 2; j++)
                acc[i][j] = __builtin_amdgcn_mfma_f32_16x16x32_bf16(
                    af[i], bw[j], acc[i][j], 0, 0, 0);
    }

#pragma unroll
    for (int i = 0; i < 4; i++)
#pragma unroll
        for (int j = 0; j < 2; j++)
#pragma unroll
            for (int r = 0; r < 4; r++) {
                const int ml = wm * 64 + i * 16 + quad * 4 + r;
                const int nl = wn * 32 + j * 16 + ln;
                Cp[(size_t)ml * ldc + nl] = (CT)acc[i][j][r];
            }
}

// Stage 1: comb[ctx][m][0:1536] = X_ctx @ W_ctx^T (bf16 out).  768 GEMM
// blocks (128x64 tiles, 3/CU) XCD-swizzled (768 = 8*96; per-XCD chunk:
// 24 bx x 4 by -> B 3MB + A 1MB = 4MB = one L2), PLUS 2048 trailing blocks
// converting W_local/W_global -> Wout bf16.  1-D grid 2816.
__global__ __launch_bounds__(256) void gemm_qkv(const __bf16* __restrict__ Xbf,
                                                const __bf16* __restrict__ Wqkv,
                                                __bf16* __restrict__ comb,
                                                const float* __restrict__ W_local,
                                                const float* __restrict__ W_global,
                                                __bf16* __restrict__ Wout)
{
    const int flat = blockIdx.x;
    if (flat >= 768) {
        const int c = flat - 768;                    // 0..2047
        const int j0 = ((c & 1023) * 256 + threadIdx.x) * 8;
        const float* src = (c < 1024) ? W_local : W_global;
        __bf16* dst = Wout + ((c < 1024) ? 0 : 2097152);
        *(bf16x8*)(dst + j0) = cvt8(src + j0);       // 1024*2048 = 2097152 exact
        return;
    }
    const int l  = (flat % 8) * 96 + flat / 8;
    const int bx = l % 24, by = (l / 24) % 16, z = l / 384;
    const __bf16* A = Xbf  + (size_t)z * 2048 * 1024 + (size_t)by * 128 * 1024;
    const __bf16* B = Wqkv + (size_t)z * 1536 * 1024 + (size_t)bx * 64 * 1024;
    __bf16* C = comb + (size_t)z * 2048 * 1536 +
                (size_t)by * 128 * 1536 + (size_t)bx * 64;
    gemm_core<__bf16>(A, 1024, B, 1024, C, 1536, 1024);
}

// Stage 4: Y[kh] = AO[:, kh*1024:+1024] @ W[:, kh*1024:+1024]^T (bf16 out).
// 1024 blocks (128x64 tiles, 4/CU), XCD-bijective chunked swizzle (8*128).
__global__ __launch_bounds__(256) void gemm_out(const __bf16* __restrict__ AO,
                                                const __bf16* __restrict__ Wout,
                                                __bf16* __restrict__ Y0,
                                                __bf16* __restrict__ Y1)
{
    const int flat = blockIdx.x;
    const int l  = (flat & 7) * 128 + (flat >> 3);
    const int bx = l & 31, by = (l >> 5) & 15, kh = l >> 9;
    const __bf16* A = AO   + (size_t)by * 128 * 2048 + kh * 1024;
    const __bf16* B = Wout + (size_t)bx * 64 * 2048 + kh * 1024;
    __bf16* Y = kh ? Y1 : Y0;
    __bf16* C = Y + (size_t)by * 128 * 2048 + (size_t)bx * 64;
    gemm_core<__bf16>(A, 2048, B, 2048, C, 2048, 1024);
}

// ---------------------------------------------------------------------------
// Stage 2: rmsnorm(q over 1024, k over 256) * g, RoPE(q,k), pack (comb bf16):
//   Q (pre-scaled by 1/8) [b][s][h][ctx*64+d]
//   K [b][kv][s][ctx*64+d]   V (UNtransposed) [b][kv][s][ctx*64+d]
// grid (2048, 2), block 256.  Q/K RoPE passes vectorized (G13).
// ---------------------------------------------------------------------------
__global__ __launch_bounds__(256) void pack_qkv(
    const __bf16* __restrict__ comb,
    const float* __restrict__ fcos, const float* __restrict__ fsin,
    const float* __restrict__ g_q_lc, const float* __restrict__ g_k_lc,
    const float* __restrict__ g_q_gc, const float* __restrict__ g_k_gc,
    __bf16* __restrict__ Qb, __bf16* __restrict__ Kb, __bf16* __restrict__ Vb)
{
    const int m = blockIdx.x, ctx = blockIdx.y;
    const int b = m >> 10, s = m & 1023;
    const int tid = threadIdx.x;
    const __bf16* cr = comb + ((size_t)ctx * 2048 + m) * 1536;
    const float* gq = ctx ? g_q_gc : g_q_lc;
    const float* gk = ctx ? g_k_gc : g_k_lc;

    const bf16x4 qv = *(const bf16x4*)(cr + tid * 4);
    float sq = (float)qv[0] * (float)qv[0] + (float)qv[1] * (float)qv[1] +
               (float)qv[2] * (float)qv[2] + (float)qv[3] * (float)qv[3];
    const float kvv = (float)cr[1024 + tid];
    float sk = kvv * kvv;
#pragma unroll
    for (int off = 32; off > 0; off >>= 1) {
        sq += __shfl_down(sq, off);
        sk += __shfl_down(sk, off);
    }
    __shared__ float redq[4], redk[4];
    if ((tid & 63) == 0) { redq[tid >> 6] = sq; redk[tid >> 6] = sk; }
    __syncthreads();
    sq = redq[0] + redq[1] + redq[2] + redq[3];
    sk = redk[0] + redk[1] + redk[2] + redk[3];
    const float rq = rsqrtf(sq * (1.f / 1024.f) + 1e-5f);
    const float rk = rsqrtf(sk * (1.f / 256.f) + 1e-5f);

    // ---- Q: each thread owns 2 rope pairs = 4 elems (reuses qv) ----
    {
        const int p2 = tid * 2;              // first pair index (0..510, even)
        const int h = p2 >> 5, pi = p2 & 31; // pi even, pair2 = pi+1 same h
        const float4 gv = *(const float4*)(gq + tid * 4);
        const float2 cv = *(const float2*)(fcos + s * 32 + pi);
        const float2 sv = *(const float2*)(fsin + s * 32 + pi);
        const float x00 = (float)qv[0] * rq * gv.x;
        const float x01 = (float)qv[1] * rq * gv.y;
        const float x10 = (float)qv[2] * rq * gv.z;
        const float x11 = (float)qv[3] * rq * gv.w;
        bf16x4 o;
        o[0] = (__bf16)((x00 * cv.x - x01 * sv.x) * 0.125f);
        o[1] = (__bf16)((x00 * sv.x + x01 * cv.x) * 0.125f);
        o[2] = (__bf16)((x10 * cv.y - x11 * sv.y) * 0.125f);
        o[3] = (__bf16)((x10 * sv.y + x11 * cv.y) * 0.125f);
        *(bf16x4*)(Qb + ((size_t)m * 16 + h) * 128 + ctx * 64 + 2 * pi) = o;
    }
    // ---- K: threads 0..63, each owns 2 rope pairs = 4 elems ----
    if (tid < 64) {
        const int p2 = tid * 2;              // pair index within K (0..126)
        const int kvh = p2 >> 5, pi = p2 & 31;
        const bf16x4 kv4 = *(const bf16x4*)(cr + 1024 + tid * 4);
        const float4 gv = *(const float4*)(gk + tid * 4);
        const float2 cv = *(const float2*)(fcos + s * 32 + pi);
        const float2 sv = *(const float2*)(fsin + s * 32 + pi);
        const float x00 = (float)kv4[0] * rk * gv.x;
        const float x01 = (float)kv4[1] * rk * gv.y;
        const float x10 = (float)kv4[2] * rk * gv.z;
        const float x11 = (float)kv4[3] * rk * gv.w;
        bf16x4 o;
        o[0] = (__bf16)(x00 * cv.x - x01 * sv.x);
        o[1] = (__bf16)(x00 * sv.x + x01 * cv.x);
        o[2] = (__bf16)(x10 * cv.y - x11 * sv.y);
        o[3] = (__bf16)(x10 * sv.y + x11 * cv.y);
        *(bf16x4*)(Kb + ((size_t)(b * 4 + kvh) * 1024 + s) * 128 + ctx * 64 + 2 * pi) = o;
    }
    {
        // coalesced: 64 lanes write 128B contiguous per kvh
        const int kvh = tid >> 6, d = tid & 63;
        Vb[((size_t)(b * 4 + kvh) * 1024 + s) * 128 + ctx * 64 + d] = cr[1280 + tid];
    }
}

// ---------------------------------------------------------------------------
// Stage 2b: V transpose  Vb[b,kv][s][128] -> Vtb[b,kv][128][s].
// 64x64 bf16 tiles via LDS; chunk-rotation swizzle. grid (16, 2, 8), blk 256.
// ---------------------------------------------------------------------------
__global__ __launch_bounds__(256) void v_transpose(const __bf16* __restrict__ Vb,
                                                   __bf16* __restrict__ Vtb)
{
    __shared__ __bf16 lds[64 * 64];
    const int st  = blockIdx.x;   // s-tile (16)
    const int dt  = blockIdx.y;   // d-tile (2) == ctx half
    const int bkv = blockIdx.z;   // b*4+kv (8)
    const int tid = threadIdx.x;
    const __bf16* src = Vb  + ((size_t)bkv * 1024 + st * 64) * 128 + dt * 64;
    __bf16*       dst = Vtb + ((size_t)bkv * 128 + dt * 64) * 1024 + st * 64;

#pragma unroll
    for (int i = 0; i < 2; i++) {
        const int c = tid + i * 256;
        const int s_in = c >> 3, ch = c & 7;
        const bf16x8 v = *(const bf16x8*)(src + (size_t)s_in * 128 + ch * 8);
        *(bf16x8*)&lds[s_in * 64 + (((ch + (s_in >> 3)) & 7) * 8)] = v;
    }
    __syncthreads();
#pragma unroll
    for (int i = 0; i < 2; i++) {
        const int c = tid + i * 256;
        const int dd = c >> 3, s0 = (c & 7) * 8;
        bf16x8 o;
#pragma unroll
        for (int jj = 0; jj < 8; jj++) {
            const int s = s0 + jj;
            o[jj] = lds[s * 64 + ((((dd >> 3) + (s >> 3)) & 7) * 8) + (dd & 7)];
        }
        *(bf16x8*)(dst + (size_t)dd * 1024 + s0) = o;
    }
}

// ---------------------------------------------------------------------------
// Stage 3: flash attention, FIXED-MAX softmax (Q pre-scaled by 1/8).
// grid (16,16,2) XCD-swizzled, block 512 = 8 waves (wq=w>>1: 16 q-rows,
// wk=w&1: kv-half).  K/V staged via global_load_lds DIRECT into UNPADDED
// XOR-swizzled LDS (linear dest + inverse-swizzled global source + XOR on
// read) -> conflict-free.  Wave-private P, one barrier/tile.
// r6-PROVEN at 40.3 us — FROZEN (r2/r4/r8: direct-global MFMA operands and
// VGPR caps all regress; this is the validated local optimum).
// ---------------------------------------------------------------------------
__global__ __launch_bounds__(512, 4) void attn(const __bf16* __restrict__ Qb,
                                               const __bf16* __restrict__ Kb,
                                               const __bf16* __restrict__ Vtb,
                                               __bf16* __restrict__ AO)
{
    __shared__ __align__(16) char smem[75264];
    __bf16* Ks   = (__bf16*)smem;             // [2][64][128] swizzled (32768 B)
    __bf16* Vts  = (__bf16*)(smem + 32768);   // [2][128][64] swizzled (32768 B)
    __bf16* Ps   = (__bf16*)(smem + 65536);   // [8][16][36]           (9216 B)
    float*  Lsum = (float*)(smem + 74752);    // [2][4][16]            (512 B)

    const int tid  = threadIdx.x;
    const int w    = tid >> 6;
    const int wq   = w >> 1;
    const int wk   = w & 1;
    const int lane = tid & 63;
    const int ln   = lane & 15;
    const int quad = lane >> 4;
    const int lx   = ln & 7;

    const int flat = (blockIdx.z * 16 + blockIdx.y) * 16 + blockIdx.x;
    const int lid  = (flat & 7) * 64 + (flat >> 3);
    const int qt = lid & 15, h = (lid >> 4) & 15, b = lid >> 8;
    const int kv = h >> 2;

    const __bf16* Kbase = Kb  + (size_t)(b * 4 + kv) * 1024 * 128;
    const __bf16* Vbase = Vtb + (size_t)(b * 4 + kv) * 128 * 1024;

    bf16x8 qf[4];
    {
        const int qrow = qt * 64 + wq * 16 + ln;
        const __bf16* qptr = Qb + ((size_t)(b * 1024 + qrow) * 16 + h) * 128;
#pragma unroll
        for (int kc = 0; kc < 4; kc++)
            qf[kc] = *(const bf16x8*)(qptr + kc * 32 + quad * 8);
    }

    f32x4 oacc[8];
    const f32x4 zero = {0.f, 0.f, 0.f, 0.f};
#pragma unroll
    for (int j = 0; j < 8; j++) oacc[j] = zero;
    float lpart[4] = {0.f, 0.f, 0.f, 0.f};

    auto stage = [&](int buf, int kt) {
        const int ks0 = kt * 64;
#pragma unroll
        for (int i = 0; i < 2; i++) {
            const int l = tid + i * 512;                 // chunk id 0..1023
            const int kr = l >> 4, kx = l & 15;          // K row / phys chunk
            gld16(Kbase + (size_t)(ks0 + kr) * 128 + ((kx ^ (kr & 7)) * 8),
                  Ks + buf * 8192 + l * 8);
            const int vr = l >> 3, vx = l & 7;           // Vt row / phys chunk
            gld16(Vbase + (size_t)vr * 1024 + ks0 + ((vx ^ (vr & 7)) * 8),
                  Vts + buf * 8192 + l * 8);
        }
    };

    stage(0, 0);

    for (int kt = 0; kt < 16; kt++) {
        const int buf = kt & 1;
        __syncthreads();                 // buf's staging complete (1 tile old)
        if (kt + 1 < 16) stage(buf ^ 1, kt + 1);

        // ---- QK^T: this wave's kv-half (32 kv) ----
        f32x4 sacc[2];
        __builtin_amdgcn_s_setprio(1);
#pragma unroll
        for (int j = 0; j < 2; j++) {
            const __bf16* krow = Ks + buf * 8192 + (wk * 32 + j * 16 + ln) * 128;
            f32x4 a = zero;
#pragma unroll
            for (int kc = 0; kc < 4; kc++) {
                const bf16x8 kf =
                    *(const bf16x8*)(krow + (((kc * 4 + quad) ^ lx) * 8));
                a = __builtin_amdgcn_mfma_f32_16x16x32_bf16(qf[kc], kf, a, 0, 0, 0);
            }
            sacc[j] = a;
        }
        __builtin_amdgcn_s_setprio(0);

        // ---- softmax partial (fixed max), P -> WAVE-PRIVATE LDS tile ----
#pragma unroll
        for (int j = 0; j < 2; j++)
#pragma unroll
            for (int r = 0; r < 4; r++) {
                const float p = __expf(sacc[j][r] - 20.f);
                lpart[r] += p;
                Ps[(w * 16 + quad * 4 + r) * 36 + j * 16 + ln] = (__bf16)p;
            }

        // ---- PV: this wave's 32 kv x full 128 d (wave-local P) ----
        const bf16x8 pf = *(const bf16x8*)(Ps + (w * 16 + ln) * 36 + quad * 8);
        const int vco = ((wk * 4 + quad) ^ lx) * 8;
        __builtin_amdgcn_s_setprio(1);
#pragma unroll
        for (int j2 = 0; j2 < 8; j2++) {
            const bf16x8 vf =
                *(const bf16x8*)(Vts + buf * 8192 + (j2 * 16 + ln) * 64 + vco);
            oacc[j2] = __builtin_amdgcn_mfma_f32_16x16x32_bf16(pf, vf, oacc[j2], 0, 0, 0);
        }
        __builtin_amdgcn_s_setprio(0);
    }

    // ---- denominators ----
    float lrow[4];
#pragma unroll
    for (int r = 0; r < 4; r++) {
        float rs = lpart[r];
#pragma unroll
        for (int off = 1; off < 16; off <<= 1)
            rs += __shfl_xor(rs, off);
        lrow[r] = rs;
    }
    if (ln == 0) {
#pragma unroll
        for (int r = 0; r < 4; r++)
            Lsum[(wk * 4 + wq) * 16 + quad * 4 + r] = lrow[r];
    }
    __syncthreads();

    // ---- cross-wk O reduction via f32 scratch overlaid on Ks/Vts ----
    float* scr = (float*)smem;   // 64 x 132 f32 = 33792 B
    if (wk == 1) {
#pragma unroll
        for (int j2 = 0; j2 < 8; j2++)
#pragma unroll
            for (int r = 0; r < 4; r++)
                scr[(wq * 16 + quad * 4 + r) * 132 + j2 * 16 + ln] = oacc[j2][r];
    }
    __syncthreads();
    if (wk == 0) {
        float inv[4];
#pragma unroll
        for (int r = 0; r < 4; r++)
            inv[r] = 1.f / (Lsum[(0 + wq) * 16 + quad * 4 + r] +
                            Lsum[(4 + wq) * 16 + quad * 4 + r]);
#pragma unroll
        for (int j2 = 0; j2 < 8; j2++)
#pragma unroll
            for (int r = 0; r < 4; r++) {
                const float v = oacc[j2][r] +
                    scr[(wq * 16 + quad * 4 + r) * 132 + j2 * 16 + ln];
                const size_t row = (size_t)(b * 1024 + qt * 64 + wq * 16 + quad * 4 + r);
                AO[row * 2048 + h * 128 + j2 * 16 + ln] = (__bf16)(v * inv[r]);
            }
    }
}

// ---------------------------------------------------------------------------
// Stage 5: x = rmsnorm(Y0_half + Y1_half + bias, g) -> fp32 out. grid (2048,2)
// Y0/Y1 are bf16 split-K partials.
// ---------------------------------------------------------------------------
__global__ __launch_bounds__(256) void rmsnorm_out(const __bf16* __restrict__ Y0,
                                                   const __bf16* __restrict__ Y1,
                                                   const float* __restrict__ b_l,
                                                   const float* __restrict__ b_g,
                                                   const float* __restrict__ g_l,
                                                   const float* __restrict__ g_g,
                                                   float* __restrict__ out)
{
    const int m = blockIdx.x, which = blockIdx.y;
    const int tid = threadIdx.x;
    const size_t off = (size_t)m * 2048 + which * 1024 + tid * 4;
    const float* bias = which ? b_g : b_l;
    const float* g    = which ? g_g : g_l;

    const bf16x4 y0 = *(const bf16x4*)(Y0 + off);
    const bf16x4 y1 = *(const bf16x4*)(Y1 + off);
    const float4 bv = *(const float4*)(bias + tid * 4);
    float x[4];
    x[0] = (float)y0[0] + (float)y1[0] + bv.x;
    x[1] = (float)y0[1] + (float)y1[1] + bv.y;
    x[2] = (float)y0[2] + (float)y1[2] + bv.z;
    x[3] = (float)y0[3] + (float)y1[3] + bv.w;
    float ss = x[0] * x[0] + x[1] * x[1] + x[2] * x[2] + x[3] * x[3];
#pragma unroll
    for (int off2 = 32; off2 > 0; off2 >>= 1) ss += __shfl_down(ss, off2);
    __shared__ float red[4];
    if ((tid & 63) == 0) red[tid >> 6] = ss;
    __syncthreads();
    ss = red[0] + red[1] + red[2] + red[3];
    const float r = rsqrtf(ss * (1.f / 1024.f) + 1e-5f);

    const float4 gv = *(const float4*)(g + tid * 4);
    float4 o;
    o.x = x[0] * r * gv.x;
    o.y = x[1] * r * gv.y;
    o.z = x[2] * r * gv.z;
    o.w = x[3] * r * gv.w;
    *(float4*)(out + (size_t)which * 2097152 + (size_t)m * 1024 + tid * 4) = o;
}

extern "C" void kernel_launch(void* const* d_in, const int* in_sizes, int n_in,
                              void* d_out, int out_size, void* d_ws, size_t ws_size,
                              hipStream_t stream)
{
    (void)in_sizes; (void)n_in; (void)out_size; (void)ws_size;
    const float* local_c  = (const float*)d_in[0];
    const float* global_c = (const float*)d_in[1];
    const float* fcos     = (const float*)d_in[2];
    const float* fsin     = (const float*)d_in[3];
    const float* W_lc     = (const float*)d_in[4];
    const float* W_gc     = (const float*)d_in[5];
    const float* g_q_lc   = (const float*)d_in[6];
    const float* g_k_lc   = (const float*)d_in[7];
    const float* g_q_gc   = (const float*)d_in[8];
    const float* g_k_gc   = (const float*)d_in[9];
    const float* W_local  = (const float*)d_in[10];
    const float* b_local  = (const float*)d_in[11];
    const float* g_lc_out = (const float*)d_in[12];
    const float* W_global = (const float*)d_in[13];
    const float* b_global = (const float*)d_in[14];
    const float* g_gc_out = (const float*)d_in[15];

    char* ws = (char*)d_ws;
    __bf16* Wout = (__bf16*)(ws + 0);          //  8388608 B
    __bf16* Xbf  = (__bf16*)(ws + 8388608);    //  8388608 B
    __bf16* Wqkv = (__bf16*)(ws + 16777216);   //  6291456 B
    __bf16* comb = (__bf16*)(ws + 23068672);   // 12582912 B
    __bf16* Qb   = (__bf16*)(ws + 35651584);   //  8388608 B
    __bf16* Kb   = (__bf16*)(ws + 44040192);   //  2097152 B
    __bf16* Vtb  = (__bf16*)(ws + 46137344);   //  2097152 B
    __bf16* AO   = (__bf16*)(ws + 48234496);   //  8388608 B
    __bf16* Y0   = (__bf16*)(ws + 56623104);   //  8388608 B
    __bf16* Y1   = (__bf16*)(ws + 65011712);   //  8388608 B
    // Vb (untransposed V, 2 MB) aliases Y0: dead before gemm_out writes Y0.
    __bf16* Vb   = (__bf16*)(ws + 56623104);

    CvtArgs ca;
    ca.s[0] = local_c;  ca.d[0] = Xbf;            ca.n[0] = 2097152;
    ca.s[1] = global_c; ca.d[1] = Xbf + 2097152;  ca.n[1] = 2097152;
    ca.s[2] = W_lc;     ca.d[2] = Wqkv;           ca.n[2] = 1572864;
    ca.s[3] = W_gc;     ca.d[3] = Wqkv + 1572864; ca.n[3] = 1572864;

    cvt_bf16<<<dim3(1024, 4), 256, 0, stream>>>(ca);
    gemm_qkv<<<dim3(2816), 256, 0, stream>>>(Xbf, Wqkv, comb,
                                             W_local, W_global, Wout);
    pack_qkv<<<dim3(2048, 2), 256, 0, stream>>>(comb, fcos, fsin,
                                                g_q_lc, g_k_lc, g_q_gc, g_k_gc,
                                                Qb, Kb, Vb);
    v_transpose<<<dim3(16, 2, 8), 256, 0, stream>>>(Vb, Vtb);
    attn<<<dim3(16, 16, 2), 512, 0, stream>>>(Qb, Kb, Vtb, AO);
    gemm_out<<<dim3(1024), 256, 0, stream>>>(AO, Wout, Y0, Y1);
    rmsnorm_out<<<dim3(2048, 2), 256, 0, stream>>>(Y0, Y1, b_local, b_global,
                                                   g_lc_out, g_gc_out,
                                                   (float*)d_out);
}

// Round 12
// 204.563 us; speedup vs baseline: 1.0870x; 1.0870x over previous
//
#include <hip/hip_runtime.h>

typedef __attribute__((ext_vector_type(8))) __bf16 bf16x8;
typedef __attribute__((ext_vector_type(4))) __bf16 bf16x4;
typedef __attribute__((ext_vector_type(4))) float f32x4;

__device__ __forceinline__ bf16x8 cvt8(const float* __restrict__ p)
{
    const float4 a = *(const float4*)p;
    const float4 b = *(const float4*)(p + 4);
    bf16x8 r;
    r[0] = (__bf16)a.x; r[1] = (__bf16)a.y; r[2] = (__bf16)a.z; r[3] = (__bf16)a.w;
    r[4] = (__bf16)b.x; r[5] = (__bf16)b.y; r[6] = (__bf16)b.z; r[7] = (__bf16)b.w;
    return r;
}

// async 16B global->LDS (global_load_lds_dwordx4); LDS dest wave-uniform base
// + lane*16 (lane-contiguous chunks, unpadded LDS). Global source IS per-lane.
__device__ __forceinline__ void gld16(const __bf16* g, __bf16* l)
{
    __builtin_amdgcn_global_load_lds(
        (const __attribute__((address_space(1))) void*)g,
        (__attribute__((address_space(3))) void*)l, 16, 0, 0);
}

// ---------------------------------------------------------------------------
// Stage 0: fp32 -> bf16 conversion of X and Wqkv only (Wout conversion is
// folded into the gemm_qkv launch). grid (1024, 4) x 256.
// ---------------------------------------------------------------------------
struct CvtArgs {
    const float* s[4];
    __bf16* d[4];
    int n[4];
};

__global__ __launch_bounds__(256) void cvt_bf16(CvtArgs a)
{
    const int t = blockIdx.y;
    const int i0 = (blockIdx.x * 256 + threadIdx.x) * 8;
    if (i0 < a.n[t])
        *(bf16x8*)(a.d[t] + i0) = cvt8(a.s[t] + i0);
}

// ---------------------------------------------------------------------------
// 128x128 bf16 GEMM core (proven config), double-buffered gld16 staging,
// BK=32, ONE barrier per K-step. Block=256 (4 waves 2x2), wave 64x64 via
// 4x4 MFMA 16x16x32.  C = A @ B^T, C type CT.
// CONFIRMED LOCAL OPTIMUM: split-K (r7, -5us) and 128x64 tiles (r11, -16us)
// both regress — per-block efficiency dominates occupancy at this size.
// ---------------------------------------------------------------------------
template <typename CT>
__device__ __forceinline__ void gemm_core(const __bf16* __restrict__ Ap, int lda,
                                          const __bf16* __restrict__ Bp, int ldb,
                                          CT* __restrict__ Cp, int ldc, int K)
{
    __shared__ __bf16 As[2][128 * 32];
    __shared__ __bf16 Bs[2][128 * 32];
    const int tid  = threadIdx.x;
    const int w    = tid >> 6;
    const int lane = tid & 63;
    const int ln   = lane & 15;
    const int quad = lane >> 4;
    const int wm   = w & 1;
    const int wn   = w >> 1;

    const int srow = 32 * w + (lane >> 2);
    const int scol = (lane & 3) * 8;

    f32x4 acc[4][4];
    const f32x4 zero = {0.f, 0.f, 0.f, 0.f};
#pragma unroll
    for (int i = 0; i < 4; i++)
#pragma unroll
        for (int j = 0; j < 4; j++) acc[i][j] = zero;

    auto stage = [&](int buf, int k0) {
        gld16(Ap + (size_t)srow * lda        + k0 + scol, As[buf] + (2 * w)     * 512 + lane * 8);
        gld16(Ap + (size_t)(srow + 16) * lda + k0 + scol, As[buf] + (2 * w + 1) * 512 + lane * 8);
        gld16(Bp + (size_t)srow * ldb        + k0 + scol, Bs[buf] + (2 * w)     * 512 + lane * 8);
        gld16(Bp + (size_t)(srow + 16) * ldb + k0 + scol, Bs[buf] + (2 * w + 1) * 512 + lane * 8);
    };

    stage(0, 0);
    int buf = 0;
    for (int k0 = 0; k0 < K; k0 += 32, buf ^= 1) {
        __syncthreads();
        if (k0 + 32 < K) stage(buf ^ 1, k0 + 32);

        bf16x8 af[4], bw[4];
#pragma unroll
        for (int i = 0; i < 4; i++)
            af[i] = *(const bf16x8*)(As[buf] + (wm * 64 + i * 16 + ln) * 32 + quad * 8);
#pragma unroll
        for (int j = 0; j < 4; j++)
            bw[j] = *(const bf16x8*)(Bs[buf] + (wn * 64 + j * 16 + ln) * 32 + quad * 8);
#pragma unroll
        for (int i = 0; i < 4; i++)
#pragma unroll
            for (int j = 0; j < 4; j++)
                acc[i][j] = __builtin_amdgcn_mfma_f32_16x16x32_bf16(
                    af[i], bw[j], acc[i][j], 0, 0, 0);
    }

#pragma unroll
    for (int i = 0; i < 4; i++)
#pragma unroll
        for (int j = 0; j < 4; j++)
#pragma unroll
            for (int r = 0; r < 4; r++) {
                const int ml = wm * 64 + i * 16 + quad * 4 + r;
                const int nl = wn * 64 + j * 16 + ln;
                Cp[(size_t)ml * ldc + nl] = (CT)acc[i][j][r];
            }
}

// Stage 1: comb[ctx][m][0:1536] = X_ctx @ W_ctx^T (bf16 out), XCD-swizzled
// (384 GEMM blocks), PLUS 2048 trailing blocks converting W_local/W_global
// -> Wout bf16 (independent of everything until gemm_out, 3 launches later —
// rides in gemm_qkv's tail instead of a serial cvt pass).  1-D grid 2432.
__global__ __launch_bounds__(256) void gemm_qkv(const __bf16* __restrict__ Xbf,
                                                const __bf16* __restrict__ Wqkv,
                                                __bf16* __restrict__ comb,
                                                const float* __restrict__ W_local,
                                                const float* __restrict__ W_global,
                                                __bf16* __restrict__ Wout)
{
    const int flat = blockIdx.x;
    if (flat >= 384) {
        const int c = flat - 384;                    // 0..2047
        const int j0 = ((c & 1023) * 256 + threadIdx.x) * 8;
        const float* src = (c < 1024) ? W_local : W_global;
        __bf16* dst = Wout + ((c < 1024) ? 0 : 2097152);
        *(bf16x8*)(dst + j0) = cvt8(src + j0);       // 1024*2048 = 2097152 exact
        return;
    }
    const int l  = (flat % 8) * 48 + flat / 8;
    const int bx = l % 12, by = (l / 12) % 16, z = l / 192;
    const __bf16* A = Xbf  + (size_t)z * 2048 * 1024 + (size_t)by * 128 * 1024;
    const __bf16* B = Wqkv + (size_t)z * 1536 * 1024 + (size_t)bx * 128 * 1024;
    __bf16* C = comb + (size_t)z * 2048 * 1536 +
                (size_t)by * 128 * 1536 + (size_t)bx * 128;
    gemm_core<__bf16>(A, 1024, B, 1024, C, 1536, 1024);
}

// Stage 4: Y[kh] = AO[:, kh*1024:+1024] @ W[:, kh*1024:+1024]^T (bf16 out).
// grid (16,16,2).  XCD swizzle with 8x8 (bx,by) chunk per XCD: A-panels
// 8x0.25MB + B-panels 8x0.25MB = 4MB = exactly one XCD L2.
__global__ __launch_bounds__(256) void gemm_out(const __bf16* __restrict__ AO,
                                                const __bf16* __restrict__ Wout,
                                                __bf16* __restrict__ Y0,
                                                __bf16* __restrict__ Y1)
{
    const int flat = (blockIdx.z * 16 + blockIdx.y) * 16 + blockIdx.x;
    const int xcd = flat & 7, r = flat >> 3;
    const int bx = (r & 7)        | ((xcd & 1) << 3);
    const int by = ((r >> 3) & 7) | ((xcd & 2) << 2);
    const int kh = xcd >> 2;
    const __bf16* A = AO   + (size_t)by * 128 * 2048 + kh * 1024;
    const __bf16* B = Wout + (size_t)bx * 128 * 2048 + kh * 1024;
    __bf16* Y = kh ? Y1 : Y0;
    __bf16* C = Y + (size_t)by * 128 * 2048 + (size_t)bx * 128;
    gemm_core<__bf16>(A, 2048, B, 2048, C, 2048, 1024);
}

// ---------------------------------------------------------------------------
// Stage 2: rmsnorm(q over 1024, k over 256) * g, RoPE(q,k), pack (comb bf16):
//   Q (pre-scaled by 1/8) [b][s][h][ctx*64+d]
//   K [b][kv][s][ctx*64+d]   V (UNtransposed) [b][kv][s][ctx*64+d]
// grid (2048, 2), block 256.  Q/K RoPE passes vectorized (G13).
// ---------------------------------------------------------------------------
__global__ __launch_bounds__(256) void pack_qkv(
    const __bf16* __restrict__ comb,
    const float* __restrict__ fcos, const float* __restrict__ fsin,
    const float* __restrict__ g_q_lc, const float* __restrict__ g_k_lc,
    const float* __restrict__ g_q_gc, const float* __restrict__ g_k_gc,
    __bf16* __restrict__ Qb, __bf16* __restrict__ Kb, __bf16* __restrict__ Vb)
{
    const int m = blockIdx.x, ctx = blockIdx.y;
    const int b = m >> 10, s = m & 1023;
    const int tid = threadIdx.x;
    const __bf16* cr = comb + ((size_t)ctx * 2048 + m) * 1536;
    const float* gq = ctx ? g_q_gc : g_q_lc;
    const float* gk = ctx ? g_k_gc : g_k_lc;

    const bf16x4 qv = *(const bf16x4*)(cr + tid * 4);
    float sq = (float)qv[0] * (float)qv[0] + (float)qv[1] * (float)qv[1] +
               (float)qv[2] * (float)qv[2] + (float)qv[3] * (float)qv[3];
    const float kvv = (float)cr[1024 + tid];
    float sk = kvv * kvv;
#pragma unroll
    for (int off = 32; off > 0; off >>= 1) {
        sq += __shfl_down(sq, off);
        sk += __shfl_down(sk, off);
    }
    __shared__ float redq[4], redk[4];
    if ((tid & 63) == 0) { redq[tid >> 6] = sq; redk[tid >> 6] = sk; }
    __syncthreads();
    sq = redq[0] + redq[1] + redq[2] + redq[3];
    sk = redk[0] + redk[1] + redk[2] + redk[3];
    const float rq = rsqrtf(sq * (1.f / 1024.f) + 1e-5f);
    const float rk = rsqrtf(sk * (1.f / 256.f) + 1e-5f);

    // ---- Q: each thread owns 2 rope pairs = 4 elems (reuses qv) ----
    {
        const int p2 = tid * 2;              // first pair index (0..510, even)
        const int h = p2 >> 5, pi = p2 & 31; // pi even, pair2 = pi+1 same h
        const float4 gv = *(const float4*)(gq + tid * 4);
        const float2 cv = *(const float2*)(fcos + s * 32 + pi);
        const float2 sv = *(const float2*)(fsin + s * 32 + pi);
        const float x00 = (float)qv[0] * rq * gv.x;
        const float x01 = (float)qv[1] * rq * gv.y;
        const float x10 = (float)qv[2] * rq * gv.z;
        const float x11 = (float)qv[3] * rq * gv.w;
        bf16x4 o;
        o[0] = (__bf16)((x00 * cv.x - x01 * sv.x) * 0.125f);
        o[1] = (__bf16)((x00 * sv.x + x01 * cv.x) * 0.125f);
        o[2] = (__bf16)((x10 * cv.y - x11 * sv.y) * 0.125f);
        o[3] = (__bf16)((x10 * sv.y + x11 * cv.y) * 0.125f);
        *(bf16x4*)(Qb + ((size_t)m * 16 + h) * 128 + ctx * 64 + 2 * pi) = o;
    }
    // ---- K: threads 0..63, each owns 2 rope pairs = 4 elems ----
    if (tid < 64) {
        const int p2 = tid * 2;              // pair index within K (0..126)
        const int kvh = p2 >> 5, pi = p2 & 31;
        const bf16x4 kv4 = *(const bf16x4*)(cr + 1024 + tid * 4);
        const float4 gv = *(const float4*)(gk + tid * 4);
        const float2 cv = *(const float2*)(fcos + s * 32 + pi);
        const float2 sv = *(const float2*)(fsin + s * 32 + pi);
        const float x00 = (float)kv4[0] * rk * gv.x;
        const float x01 = (float)kv4[1] * rk * gv.y;
        const float x10 = (float)kv4[2] * rk * gv.z;
        const float x11 = (float)kv4[3] * rk * gv.w;
        bf16x4 o;
        o[0] = (__bf16)(x00 * cv.x - x01 * sv.x);
        o[1] = (__bf16)(x00 * sv.x + x01 * cv.x);
        o[2] = (__bf16)(x10 * cv.y - x11 * sv.y);
        o[3] = (__bf16)(x10 * sv.y + x11 * cv.y);
        *(bf16x4*)(Kb + ((size_t)(b * 4 + kvh) * 1024 + s) * 128 + ctx * 64 + 2 * pi) = o;
    }
    {
        // coalesced: 64 lanes write 128B contiguous per kvh
        const int kvh = tid >> 6, d = tid & 63;
        Vb[((size_t)(b * 4 + kvh) * 1024 + s) * 128 + ctx * 64 + d] = cr[1280 + tid];
    }
}

// ---------------------------------------------------------------------------
// Stage 2b: V transpose  Vb[b,kv][s][128] -> Vtb[b,kv][128][s].
// 64x64 bf16 tiles via LDS; chunk-rotation swizzle. grid (16, 2, 8), blk 256.
// ---------------------------------------------------------------------------
__global__ __launch_bounds__(256) void v_transpose(const __bf16* __restrict__ Vb,
                                                   __bf16* __restrict__ Vtb)
{
    __shared__ __bf16 lds[64 * 64];
    const int st  = blockIdx.x;   // s-tile (16)
    const int dt  = blockIdx.y;   // d-tile (2) == ctx half
    const int bkv = blockIdx.z;   // b*4+kv (8)
    const int tid = threadIdx.x;
    const __bf16* src = Vb  + ((size_t)bkv * 1024 + st * 64) * 128 + dt * 64;
    __bf16*       dst = Vtb + ((size_t)bkv * 128 + dt * 64) * 1024 + st * 64;

#pragma unroll
    for (int i = 0; i < 2; i++) {
        const int c = tid + i * 256;
        const int s_in = c >> 3, ch = c & 7;
        const bf16x8 v = *(const bf16x8*)(src + (size_t)s_in * 128 + ch * 8);
        *(bf16x8*)&lds[s_in * 64 + (((ch + (s_in >> 3)) & 7) * 8)] = v;
    }
    __syncthreads();
#pragma unroll
    for (int i = 0; i < 2; i++) {
        const int c = tid + i * 256;
        const int dd = c >> 3, s0 = (c & 7) * 8;
        bf16x8 o;
#pragma unroll
        for (int jj = 0; jj < 8; jj++) {
            const int s = s0 + jj;
            o[jj] = lds[s * 64 + ((((dd >> 3) + (s >> 3)) & 7) * 8) + (dd & 7)];
        }
        *(bf16x8*)(dst + (size_t)dd * 1024 + s0) = o;
    }
}

// ---------------------------------------------------------------------------
// Stage 3: flash attention, FIXED-MAX softmax (Q pre-scaled by 1/8).
// grid (16,16,2) XCD-swizzled, block 512 = 8 waves (wq=w>>1: 16 q-rows,
// wk=w&1: kv-half).  K/V staged via global_load_lds DIRECT into UNPADDED
// XOR-swizzled LDS (linear dest + inverse-swizzled global source + XOR on
// read) -> conflict-free.  Wave-private P, one barrier/tile.
// r6-PROVEN at 40.3 us — FROZEN (r2/r4/r8: direct-global MFMA operands and
// VGPR caps all regress; this is the validated local optimum).
// ---------------------------------------------------------------------------
__global__ __launch_bounds__(512, 4) void attn(const __bf16* __restrict__ Qb,
                                               const __bf16* __restrict__ Kb,
                                               const __bf16* __restrict__ Vtb,
                                               __bf16* __restrict__ AO)
{
    __shared__ __align__(16) char smem[75264];
    __bf16* Ks   = (__bf16*)smem;             // [2][64][128] swizzled (32768 B)
    __bf16* Vts  = (__bf16*)(smem + 32768);   // [2][128][64] swizzled (32768 B)
    __bf16* Ps   = (__bf16*)(smem + 65536);   // [8][16][36]           (9216 B)
    float*  Lsum = (float*)(smem + 74752);    // [2][4][16]            (512 B)

    const int tid  = threadIdx.x;
    const int w    = tid >> 6;
    const int wq   = w >> 1;
    const int wk   = w & 1;
    const int lane = tid & 63;
    const int ln   = lane & 15;
    const int quad = lane >> 4;
    const int lx   = ln & 7;

    const int flat = (blockIdx.z * 16 + blockIdx.y) * 16 + blockIdx.x;
    const int lid  = (flat & 7) * 64 + (flat >> 3);
    const int qt = lid & 15, h = (lid >> 4) & 15, b = lid >> 8;
    const int kv = h >> 2;

    const __bf16* Kbase = Kb  + (size_t)(b * 4 + kv) * 1024 * 128;
    const __bf16* Vbase = Vtb + (size_t)(b * 4 + kv) * 128 * 1024;

    bf16x8 qf[4];
    {
        const int qrow = qt * 64 + wq * 16 + ln;
        const __bf16* qptr = Qb + ((size_t)(b * 1024 + qrow) * 16 + h) * 128;
#pragma unroll
        for (int kc = 0; kc < 4; kc++)
            qf[kc] = *(const bf16x8*)(qptr + kc * 32 + quad * 8);
    }

    f32x4 oacc[8];
    const f32x4 zero = {0.f, 0.f, 0.f, 0.f};
#pragma unroll
    for (int j = 0; j < 8; j++) oacc[j] = zero;
    float lpart[4] = {0.f, 0.f, 0.f, 0.f};

    auto stage = [&](int buf, int kt) {
        const int ks0 = kt * 64;
#pragma unroll
        for (int i = 0; i < 2; i++) {
            const int l = tid + i * 512;                 // chunk id 0..1023
            const int kr = l >> 4, kx = l & 15;          // K row / phys chunk
            gld16(Kbase + (size_t)(ks0 + kr) * 128 + ((kx ^ (kr & 7)) * 8),
                  Ks + buf * 8192 + l * 8);
            const int vr = l >> 3, vx = l & 7;           // Vt row / phys chunk
            gld16(Vbase + (size_t)vr * 1024 + ks0 + ((vx ^ (vr & 7)) * 8),
                  Vts + buf * 8192 + l * 8);
        }
    };

    stage(0, 0);

    for (int kt = 0; kt < 16; kt++) {
        const int buf = kt & 1;
        __syncthreads();                 // buf's staging complete (1 tile old)
        if (kt + 1 < 16) stage(buf ^ 1, kt + 1);

        // ---- QK^T: this wave's kv-half (32 kv) ----
        f32x4 sacc[2];
        __builtin_amdgcn_s_setprio(1);
#pragma unroll
        for (int j = 0; j < 2; j++) {
            const __bf16* krow = Ks + buf * 8192 + (wk * 32 + j * 16 + ln) * 128;
            f32x4 a = zero;
#pragma unroll
            for (int kc = 0; kc < 4; kc++) {
                const bf16x8 kf =
                    *(const bf16x8*)(krow + (((kc * 4 + quad) ^ lx) * 8));
                a = __builtin_amdgcn_mfma_f32_16x16x32_bf16(qf[kc], kf, a, 0, 0, 0);
            }
            sacc[j] = a;
        }
        __builtin_amdgcn_s_setprio(0);

        // ---- softmax partial (fixed max), P -> WAVE-PRIVATE LDS tile ----
#pragma unroll
        for (int j = 0; j < 2; j++)
#pragma unroll
            for (int r = 0; r < 4; r++) {
                const float p = __expf(sacc[j][r] - 20.f);
                lpart[r] += p;
                Ps[(w * 16 + quad * 4 + r) * 36 + j * 16 + ln] = (__bf16)p;
            }

        // ---- PV: this wave's 32 kv x full 128 d (wave-local P) ----
        const bf16x8 pf = *(const bf16x8*)(Ps + (w * 16 + ln) * 36 + quad * 8);
        const int vco = ((wk * 4 + quad) ^ lx) * 8;
        __builtin_amdgcn_s_setprio(1);
#pragma unroll
        for (int j2 = 0; j2 < 8; j2++) {
            const bf16x8 vf =
                *(const bf16x8*)(Vts + buf * 8192 + (j2 * 16 + ln) * 64 + vco);
            oacc[j2] = __builtin_amdgcn_mfma_f32_16x16x32_bf16(pf, vf, oacc[j2], 0, 0, 0);
        }
        __builtin_amdgcn_s_setprio(0);
    }

    // ---- denominators ----
    float lrow[4];
#pragma unroll
    for (int r = 0; r < 4; r++) {
        float rs = lpart[r];
#pragma unroll
        for (int off = 1; off < 16; off <<= 1)
            rs += __shfl_xor(rs, off);
        lrow[r] = rs;
    }
    if (ln == 0) {
#pragma unroll
        for (int r = 0; r < 4; r++)
            Lsum[(wk * 4 + wq) * 16 + quad * 4 + r] = lrow[r];
    }
    __syncthreads();

    // ---- cross-wk O reduction via f32 scratch overlaid on Ks/Vts ----
    float* scr = (float*)smem;   // 64 x 132 f32 = 33792 B
    if (wk == 1) {
#pragma unroll
        for (int j2 = 0; j2 < 8; j2++)
#pragma unroll
            for (int r = 0; r < 4; r++)
                scr[(wq * 16 + quad * 4 + r) * 132 + j2 * 16 + ln] = oacc[j2][r];
    }
    __syncthreads();
    if (wk == 0) {
        float inv[4];
#pragma unroll
        for (int r = 0; r < 4; r++)
            inv[r] = 1.f / (Lsum[(0 + wq) * 16 + quad * 4 + r] +
                            Lsum[(4 + wq) * 16 + quad * 4 + r]);
#pragma unroll
        for (int j2 = 0; j2 < 8; j2++)
#pragma unroll
            for (int r = 0; r < 4; r++) {
                const float v = oacc[j2][r] +
                    scr[(wq * 16 + quad * 4 + r) * 132 + j2 * 16 + ln];
                const size_t row = (size_t)(b * 1024 + qt * 64 + wq * 16 + quad * 4 + r);
                AO[row * 2048 + h * 128 + j2 * 16 + ln] = (__bf16)(v * inv[r]);
            }
    }
}

// ---------------------------------------------------------------------------
// Stage 5: x = rmsnorm(Y0_half + Y1_half + bias, g) -> fp32 out. grid (2048,2)
// Y0/Y1 are bf16 split-K partials.
// ---------------------------------------------------------------------------
__global__ __launch_bounds__(256) void rmsnorm_out(const __bf16* __restrict__ Y0,
                                                   const __bf16* __restrict__ Y1,
                                                   const float* __restrict__ b_l,
                                                   const float* __restrict__ b_g,
                                                   const float* __restrict__ g_l,
                                                   const float* __restrict__ g_g,
                                                   float* __restrict__ out)
{
    const int m = blockIdx.x, which = blockIdx.y;
    const int tid = threadIdx.x;
    const size_t off = (size_t)m * 2048 + which * 1024 + tid * 4;
    const float* bias = which ? b_g : b_l;
    const float* g    = which ? g_g : g_l;

    const bf16x4 y0 = *(const bf16x4*)(Y0 + off);
    const bf16x4 y1 = *(const bf16x4*)(Y1 + off);
    const float4 bv = *(const float4*)(bias + tid * 4);
    float x[4];
    x[0] = (float)y0[0] + (float)y1[0] + bv.x;
    x[1] = (float)y0[1] + (float)y1[1] + bv.y;
    x[2] = (float)y0[2] + (float)y1[2] + bv.z;
    x[3] = (float)y0[3] + (float)y1[3] + bv.w;
    float ss = x[0] * x[0] + x[1] * x[1] + x[2] * x[2] + x[3] * x[3];
#pragma unroll
    for (int off2 = 32; off2 > 0; off2 >>= 1) ss += __shfl_down(ss, off2);
    __shared__ float red[4];
    if ((tid & 63) == 0) red[tid >> 6] = ss;
    __syncthreads();
    ss = red[0] + red[1] + red[2] + red[3];
    const float r = rsqrtf(ss * (1.f / 1024.f) + 1e-5f);

    const float4 gv = *(const float4*)(g + tid * 4);
    float4 o;
    o.x = x[0] * r * gv.x;
    o.y = x[1] * r * gv.y;
    o.z = x[2] * r * gv.z;
    o.w = x[3] * r * gv.w;
    *(float4*)(out + (size_t)which * 2097152 + (size_t)m * 1024 + tid * 4) = o;
}

extern "C" void kernel_launch(void* const* d_in, const int* in_sizes, int n_in,
                              void* d_out, int out_size, void* d_ws, size_t ws_size,
                              hipStream_t stream)
{
    (void)in_sizes; (void)n_in; (void)out_size; (void)ws_size;
    const float* local_c  = (const float*)d_in[0];
    const float* global_c = (const float*)d_in[1];
    const float* fcos     = (const float*)d_in[2];
    const float* fsin     = (const float*)d_in[3];
    const float* W_lc     = (const float*)d_in[4];
    const float* W_gc     = (const float*)d_in[5];
    const float* g_q_lc   = (const float*)d_in[6];
    const float* g_k_lc   = (const float*)d_in[7];
    const float* g_q_gc   = (const float*)d_in[8];
    const float* g_k_gc   = (const float*)d_in[9];
    const float* W_local  = (const float*)d_in[10];
    const float* b_local  = (const float*)d_in[11];
    const float* g_lc_out = (const float*)d_in[12];
    const float* W_global = (const float*)d_in[13];
    const float* b_global = (const float*)d_in[14];
    const float* g_gc_out = (const float*)d_in[15];

    char* ws = (char*)d_ws;
    __bf16* Wout = (__bf16*)(ws + 0);          //  8388608 B
    __bf16* Xbf  = (__bf16*)(ws + 8388608);    //  8388608 B
    __bf16* Wqkv = (__bf16*)(ws + 16777216);   //  6291456 B
    __bf16* comb = (__bf16*)(ws + 23068672);   // 12582912 B
    __bf16* Qb   = (__bf16*)(ws + 35651584);   //  8388608 B
    __bf16* Kb   = (__bf16*)(ws + 44040192);   //  2097152 B
    __bf16* Vtb  = (__bf16*)(ws + 46137344);   //  2097152 B
    __bf16* AO   = (__bf16*)(ws + 48234496);   //  8388608 B
    __bf16* Y0   = (__bf16*)(ws + 56623104);   //  8388608 B
    __bf16* Y1   = (__bf16*)(ws + 65011712);   //  8388608 B
    // Vb (untransposed V, 2 MB) aliases Y0: dead before gemm_out writes Y0.
    __bf16* Vb   = (__bf16*)(ws + 56623104);

    CvtArgs ca;
    ca.s[0] = local_c;  ca.d[0] = Xbf;            ca.n[0] = 2097152;
    ca.s[1] = global_c; ca.d[1] = Xbf + 2097152;  ca.n[1] = 2097152;
    ca.s[2] = W_lc;     ca.d[2] = Wqkv;           ca.n[2] = 1572864;
    ca.s[3] = W_gc;     ca.d[3] = Wqkv + 1572864; ca.n[3] = 1572864;

    cvt_bf16<<<dim3(1024, 4), 256, 0, stream>>>(ca);
    gemm_qkv<<<dim3(2432), 256, 0, stream>>>(Xbf, Wqkv, comb,
                                             W_local, W_global, Wout);
    pack_qkv<<<dim3(2048, 2), 256, 0, stream>>>(comb, fcos, fsin,
                                                g_q_lc, g_k_lc, g_q_gc, g_k_gc,
                                                Qb, Kb, Vb);
    v_transpose<<<dim3(16, 2, 8), 256, 0, stream>>>(Vb, Vtb);
    attn<<<dim3(16, 16, 2), 512, 0, stream>>>(Qb, Kb, Vtb, AO);
    gemm_out<<<dim3(16, 16, 2), 256, 0, stream>>>(AO, Wout, Y0, Y1);
    rmsnorm_out<<<dim3(2048, 2), 256, 0, stream>>>(Y0, Y1, b_local, b_global,
                                                   g_lc_out, g_gc_out,
                                                   (float*)d_out);
}